// Round 8
// baseline (993.428 us; speedup 1.0000x reference)
//
#include <hip/hip_runtime.h>
#include <hip/hip_bf16.h>

#define VOCAB 29
#define VEC   512
#define HID   1024
#define SEN   64
#define BATCH 2048

typedef __bf16 bf16_t;
typedef bf16_t bf16x8 __attribute__((ext_vector_type(8)));
typedef float  floatx4 __attribute__((ext_vector_type(4)));

// ---------------- prep: W_hh fp32 -> bf16 ----------------
__global__ void cvt_whh(const float* __restrict__ w, bf16_t* __restrict__ o, int n) {
    int i = blockIdx.x * blockDim.x + threadIdx.x;
    if (i < n) o[i] = (bf16_t)w[i];
}

// ---------------- prep: W_cls fp32 [65][1024] -> bf16 padded [80][1024] ----------------
__global__ void cvt_wcls(const float* __restrict__ w, bf16_t* __restrict__ o) {
    int i = blockIdx.x * blockDim.x + threadIdx.x;
    if (i >= 80 * HID) return;
    o[i] = (i < 65 * HID) ? (bf16_t)w[i] : (bf16_t)0.0f;
}

// ---------------- prep: proj[v][h] = dot(emb[v], W_ih[h]) (fp32) ----------------
__global__ void proj_kernel(const float* __restrict__ emb, const float* __restrict__ wih,
                            float* __restrict__ proj) {
    int idx = blockIdx.x * blockDim.x + threadIdx.x;
    if (idx >= VOCAB * HID) return;
    int v = idx / HID, h = idx % HID;
    const float* e = emb + v * VEC;
    const float* w = wih + h * VEC;
    float s = 0.f;
    for (int k = 0; k < VEC; k += 4) {
        float4 ev = *(const float4*)(e + k);
        float4 wv = *(const float4*)(w + k);
        s += ev.x * wv.x + ev.y * wv.y + ev.z * wv.z + ev.w * wv.w;
    }
    proj[idx] = s;
}

// exact identity tanh(x) = 1 - 2/(exp(2x)+1)
__device__ __forceinline__ float fast_tanh(float x) {
    float e = __expf(2.0f * x);
    return 1.0f - 2.0f / (e + 1.0f);
}

// async global->LDS 16B copy (wave-uniform LDS base + lane*16). aux: CPol (SC0=1)
__device__ __forceinline__ void load16_to_lds(const bf16_t* g, bf16_t* l, int aux) {
    auto gp = reinterpret_cast<const __attribute__((address_space(1))) unsigned int*>(
        reinterpret_cast<uintptr_t>(g));
    auto lp = reinterpret_cast<__attribute__((address_space(3))) unsigned int*>(
        static_cast<unsigned int>(reinterpret_cast<uintptr_t>(l)));
    if (aux) __builtin_amdgcn_global_load_lds(gp, lp, 16, 0, 1);
    else     __builtin_amdgcn_global_load_lds(gp, lp, 16, 0, 0);
}

// =====================================================================
// PERSISTENT RNN: all 64 steps, one kernel. Grid (16,16), 256 thr = 4 waves.
// bx = m-group (128 batch rows), by = n-group (64 cols). Linear id = bx+16*by,
// XCD = id%8 = bx%8 -> all 16 n-blocks of an m-group share one XCD/L2 [m09].
// Sync: per-m-group counter flag in global (XCD-local L2), one relaxed agent
// atomicAdd per block per step after a vmcnt-draining __syncthreads; waiter
// polls. No grid.sync, no threadfence, no L2 writeback.
// B = W_hh slice (64 rows x 1024 K, bf16) LDS-resident for ALL steps
// (padded stride 1032 elems; R2-proven read pattern).
// A staged per step: DMA + XOR swizzle (R5-proven), BK=32 double-buffer,
// aux=SC0 (bypass L1; h rewritten every 2 steps by same-XCD peers).
// =====================================================================
#define PBM 128
#define PBN 64
#define PBK 32
#define BSTRIDE 1032   // 1024 + 8 bf16 pad

__global__ __launch_bounds__(256, 1)
void rnn_persist(const bf16_t* __restrict__ whh_bf, const float* __restrict__ proj,
                 const int* __restrict__ x, bf16_t* __restrict__ h0b,
                 bf16_t* __restrict__ h1b, int* __restrict__ flags)
{
    extern __shared__ __align__(16) char smem[];
    bf16_t* Bs  = (bf16_t*)smem;                            // 64*1032*2   = 132096 B
    bf16_t* As  = (bf16_t*)(smem + 132096);                 // 2*128*32*2  =  16384 B
    float*  psh = (float*) (smem + 132096 + 16384);         // 29*64*4     =   7424 B
    int*    tsh = (int*)   (smem + 132096 + 16384 + 7424);  // 128*4       =    512 B

    const int tid  = threadIdx.x;
    const int bx   = blockIdx.x, by = blockIdx.y;
    const int m0   = bx * PBM, n0 = by * PBN;
    const int wave = tid >> 6, lane = tid & 63;
    const int wm   = wave * 32;
    const int q    = lane >> 4, l16 = lane & 15;

    // ---- one-time: B slice -> LDS via DMA (64 rows x 128 chunks of 16B) ----
#pragma unroll 4
    for (int it = 0; it < 32; it++) {
        int c0 = it * 256 + wave * 64;          // wave-uniform chunk base
        int c  = c0 + lane;
        int r  = c >> 7, cc = c & 127;          // 128 chunks per row; wave never crosses a row
        load16_to_lds(whh_bf + (n0 + r) * HID + cc * 8,
                      Bs + (c0 >> 7) * BSTRIDE + (c0 & 127) * 8, 0);
    }
    // ---- one-time: proj slice ----
    for (int i = tid; i < VOCAB * 64; i += 256) {
        int v = i >> 6, j = i & 63;
        psh[v * 64 + j] = proj[v * HID + n0 + j];
    }

    // A staging constants (BK=32: 4 chunks/row, XOR swizzle g = p ^ (r&3))
    int baseA[2], dstA[2];
#pragma unroll
    for (int it = 0; it < 2; it++) {
        int c = it * 256 + wave * 64 + lane;
        int r = c >> 2, p = c & 3, g = p ^ (r & 3);
        baseA[it] = (m0 + r) * HID + g * 8;
        dstA[it]  = (it * 256 + wave * 64) * 8;
    }
    __syncthreads();   // B/proj ready (vmcnt drain)

    for (int t = 0; t < SEN; t++) {
        const bf16_t* __restrict__ hin  = (t & 1) ? h0b : h1b;
        bf16_t* __restrict__       hout = (t & 1) ? h1b : h0b;

        if (t > 0 && tid == 0) {
            const int need = 16 * t;
            while (__hip_atomic_load(flags + bx, __ATOMIC_RELAXED,
                                     __HIP_MEMORY_SCOPE_AGENT) < need)
                __builtin_amdgcn_s_sleep(4);
        }
        __syncthreads();   // releases on group-ready; separates prior tsh reads
        if (tid < PBM) tsh[tid] = x[(m0 + tid) * SEN + t];

        floatx4 acc[2][4];
#pragma unroll
        for (int i = 0; i < 2; i++)
#pragma unroll
            for (int j = 0; j < 4; j++) acc[i][j] = (floatx4){0.f, 0.f, 0.f, 0.f};

        if (t > 0) {
#pragma unroll
            for (int it = 0; it < 2; it++)
                load16_to_lds(hin + baseA[it], As + dstA[it], 1);
            __syncthreads();   // tile 0 + tsh ready
            for (int i = 0; i < 32; i++) {
                const int buf = i & 1;
                if (i < 31) {
#pragma unroll
                    for (int it = 0; it < 2; it++)
                        load16_to_lds(hin + baseA[it] + (i + 1) * PBK,
                                      As + (1 - buf) * 4096 + dstA[it], 1);
                }
                const int pq = (q ^ (l16 & 3)) * 8;
                const int kb = i * PBK + q * 8;
                bf16x8 af0 = *(const bf16x8*)(As + buf * 4096 + (wm + l16) * PBK + pq);
                bf16x8 af1 = *(const bf16x8*)(As + buf * 4096 + (wm + 16 + l16) * PBK + pq);
                bf16x8 b0  = *(const bf16x8*)(Bs + (     l16) * BSTRIDE + kb);
                bf16x8 b1  = *(const bf16x8*)(Bs + (16 + l16) * BSTRIDE + kb);
                bf16x8 b2  = *(const bf16x8*)(Bs + (32 + l16) * BSTRIDE + kb);
                bf16x8 b3  = *(const bf16x8*)(Bs + (48 + l16) * BSTRIDE + kb);
                acc[0][0] = __builtin_amdgcn_mfma_f32_16x16x32_bf16(af0, b0, acc[0][0], 0,0,0);
                acc[0][1] = __builtin_amdgcn_mfma_f32_16x16x32_bf16(af0, b1, acc[0][1], 0,0,0);
                acc[0][2] = __builtin_amdgcn_mfma_f32_16x16x32_bf16(af0, b2, acc[0][2], 0,0,0);
                acc[0][3] = __builtin_amdgcn_mfma_f32_16x16x32_bf16(af0, b3, acc[0][3], 0,0,0);
                acc[1][0] = __builtin_amdgcn_mfma_f32_16x16x32_bf16(af1, b0, acc[1][0], 0,0,0);
                acc[1][1] = __builtin_amdgcn_mfma_f32_16x16x32_bf16(af1, b1, acc[1][1], 0,0,0);
                acc[1][2] = __builtin_amdgcn_mfma_f32_16x16x32_bf16(af1, b2, acc[1][2], 0,0,0);
                acc[1][3] = __builtin_amdgcn_mfma_f32_16x16x32_bf16(af1, b3, acc[1][3], 0,0,0);
                __syncthreads();   // drains next-tile DMA + guards buffer swap
            }
        } else {
            __syncthreads();   // tsh ready
        }

        // epilogue: C/D row = q*4+reg, col = l16 (HW-verified); + proj + tanh
#pragma unroll
        for (int mi = 0; mi < 2; mi++) {
#pragma unroll
            for (int r = 0; r < 4; r++) {
                int lm = wm + mi * 16 + q * 4 + r;
                const float* ps = psh + tsh[lm] * 64;
                bf16_t* orow = hout + (m0 + lm) * HID + n0;
#pragma unroll
                for (int ni = 0; ni < 4; ni++) {
                    float v = acc[mi][ni][r] + ps[ni * 16 + l16];
                    orow[ni * 16 + l16] = (bf16_t)fast_tanh(v);
                }
            }
        }
        __syncthreads();   // all waves' stores drained (vmcnt0) before signal
        if (tid == 0)
            __hip_atomic_fetch_add(flags + bx, 1, __ATOMIC_RELAXED,
                                   __HIP_MEMORY_SCOPE_AGENT);
    }
}

// =====================================================================
// FALLBACK: proven R5 per-step kernel (64 launches) if coop launch rejects.
// =====================================================================
#define BM 128
#define BN 64
#define BK 64

__global__ __launch_bounds__(256)
void rnn_step(const bf16_t* __restrict__ h_in, const bf16_t* __restrict__ whh,
              const float* __restrict__ proj, const int* __restrict__ x,
              bf16_t* __restrict__ h_out, int t, int first)
{
    __shared__ __align__(16) bf16_t Ash[2][BM][BK];
    __shared__ __align__(16) bf16_t Bsh[2][BN][BK];
    __shared__ int tok_sh[BM];

    const int tid  = threadIdx.x;
    const int m0   = blockIdx.x * BM;
    const int n0   = blockIdx.y * BN;
    const int wave = tid >> 6;
    const int lane = tid & 63;
    const int wm   = wave * 32;
    const int q    = lane >> 4;
    const int l16  = lane & 15;

    if (tid < BM) tok_sh[tid] = x[(m0 + tid) * SEN + t];

    const bf16_t* srcA[4];
    const bf16_t* srcB[2];
    int dstA[4], dstB[2];
#pragma unroll
    for (int it = 0; it < 4; it++) {
        int c = it * 256 + wave * 64 + lane;
        int r = c >> 3, p = c & 7, g = p ^ (r & 7);
        srcA[it] = h_in + (m0 + r) * HID + g * 8;
        dstA[it] = (it * 256 + wave * 64) * 8;
    }
#pragma unroll
    for (int it = 0; it < 2; it++) {
        int c = it * 256 + wave * 64 + lane;
        int r = c >> 3, p = c & 7, g = p ^ (r & 7);
        srcB[it] = whh + (n0 + r) * HID + g * 8;
        dstB[it] = (it * 256 + wave * 64) * 8;
    }

    floatx4 acc[2][4];
#pragma unroll
    for (int i = 0; i < 2; i++)
#pragma unroll
        for (int j = 0; j < 4; j++) acc[i][j] = (floatx4){0.f, 0.f, 0.f, 0.f};

    if (!first) {
#pragma unroll
        for (int it = 0; it < 4; it++) load16_to_lds(srcA[it], &Ash[0][0][0] + dstA[it], 0);
#pragma unroll
        for (int it = 0; it < 2; it++) load16_to_lds(srcB[it], &Bsh[0][0][0] + dstB[it], 0);
    }
    __syncthreads();

    if (!first) {
        for (int i = 0; i < 16; i++) {
            const int buf = i & 1;
            if (i < 15) {
                const int koff = (i + 1) * BK;
#pragma unroll
                for (int it = 0; it < 4; it++)
                    load16_to_lds(srcA[it] + koff, &Ash[1 - buf][0][0] + dstA[it], 0);
#pragma unroll
                for (int it = 0; it < 2; it++)
                    load16_to_lds(srcB[it] + koff, &Bsh[1 - buf][0][0] + dstB[it], 0);
            }
#pragma unroll
            for (int ks = 0; ks < BK; ks += 32) {
                const int pq = (((ks >> 3) + q) ^ (l16 & 7)) * 8;
                bf16x8 af[2], bfr[4];
                af[0]  = *(const bf16x8*)&Ash[buf][wm + l16][pq];
                af[1]  = *(const bf16x8*)&Ash[buf][wm + 16 + l16][pq];
                bfr[0] = *(const bf16x8*)&Bsh[buf][l16][pq];
                bfr[1] = *(const bf16x8*)&Bsh[buf][16 + l16][pq];
                bfr[2] = *(const bf16x8*)&Bsh[buf][32 + l16][pq];
                bfr[3] = *(const bf16x8*)&Bsh[buf][48 + l16][pq];
#pragma unroll
                for (int mi = 0; mi < 2; mi++)
#pragma unroll
                    for (int ni = 0; ni < 4; ni++)
                        acc[mi][ni] = __builtin_amdgcn_mfma_f32_16x16x32_bf16(
                            af[mi], bfr[ni], acc[mi][ni], 0, 0, 0);
            }
            if (i < 15) __syncthreads();
        }
    }

#pragma unroll
    for (int mi = 0; mi < 2; mi++) {
#pragma unroll
        for (int r = 0; r < 4; r++) {
            int lm = wm + mi * 16 + q * 4 + r;
            int gm = m0 + lm;
            const float* pr = proj + tok_sh[lm] * HID;
#pragma unroll
            for (int ni = 0; ni < 4; ni++) {
                int gn = n0 + ni * 16 + l16;
                float v = acc[mi][ni][r] + pr[gn];
                h_out[gm * HID + gn] = (bf16_t)fast_tanh(v);
            }
        }
    }
}

// ---------------- classifier: out = h @ W_cls^T + b_cls via MFMA (proven) ----------------
#define CBM 128
#define CLDK 72
__global__ __launch_bounds__(256)
void classifier_mfma(const bf16_t* __restrict__ h, const bf16_t* __restrict__ wcls,
                     const float* __restrict__ bcls, float* __restrict__ out)
{
    __shared__ __align__(16) bf16_t Ash[CBM][CLDK];
    __shared__ __align__(16) bf16_t Bsh[80][CLDK];

    const int tid = threadIdx.x;
    const int m0 = blockIdx.x * CBM;
    const int wave = tid >> 6, lane = tid & 63;
    const int wm = wave * 32;
    const int q = lane >> 4, l16 = lane & 15;

    floatx4 acc[2][5];
#pragma unroll
    for (int i = 0; i < 2; i++)
#pragma unroll
        for (int j = 0; j < 5; j++) acc[i][j] = (floatx4){0.f, 0.f, 0.f, 0.f};

    for (int kk = 0; kk < HID; kk += 64) {
#pragma unroll
        for (int it = 0; it < 4; it++) {
            int idx = tid + it * 256, r = idx >> 3, c = (idx & 7) * 8;
            *(uint4*)&Ash[r][c] = *(const uint4*)&h[(m0 + r) * HID + kk + c];
        }
#pragma unroll
        for (int it = 0; it < 3; it++) {
            int idx = tid + it * 256;
            if (idx < 640) {
                int r = idx >> 3, c = (idx & 7) * 8;
                *(uint4*)&Bsh[r][c] = *(const uint4*)&wcls[r * HID + kk + c];
            }
        }
        __syncthreads();
#pragma unroll
        for (int ks = 0; ks < 64; ks += 32) {
            bf16x8 af[2], bfr[5];
#pragma unroll
            for (int mi = 0; mi < 2; mi++)
                af[mi] = *(const bf16x8*)&Ash[wm + mi * 16 + l16][ks + q * 8];
#pragma unroll
            for (int ni = 0; ni < 5; ni++)
                bfr[ni] = *(const bf16x8*)&Bsh[ni * 16 + l16][ks + q * 8];
#pragma unroll
            for (int mi = 0; mi < 2; mi++)
#pragma unroll
                for (int ni = 0; ni < 5; ni++)
                    acc[mi][ni] = __builtin_amdgcn_mfma_f32_16x16x32_bf16(
                        af[mi], bfr[ni], acc[mi][ni], 0, 0, 0);
        }
        __syncthreads();
    }

#pragma unroll
    for (int mi = 0; mi < 2; mi++) {
#pragma unroll
        for (int r = 0; r < 4; r++) {
            int gm = m0 + wm + mi * 16 + q * 4 + r;
#pragma unroll
            for (int ni = 0; ni < 5; ni++) {
                int gn = ni * 16 + l16;
                if (gn < SEN + 1)
                    out[gm * (SEN + 1) + gn] = acc[mi][ni][r] + bcls[gn];
            }
        }
    }
}

extern "C" void kernel_launch(void* const* d_in, const int* in_sizes, int n_in,
                              void* d_out, int out_size, void* d_ws, size_t ws_size,
                              hipStream_t stream)
{
    const int*   x     = (const int*)  d_in[0];
    const float* emb   = (const float*)d_in[1];
    const float* w_ih  = (const float*)d_in[2];
    const float* w_hh  = (const float*)d_in[3];
    const float* w_cls = (const float*)d_in[4];
    const float* b_cls = (const float*)d_in[5];
    float* out = (float*)d_out;

    char* ws = (char*)d_ws;
    bf16_t* whh_bf  = (bf16_t*)ws;                                  // 2 MB
    float*  proj    = (float*)(ws + (2u << 20));                    // 128 KB
    bf16_t* wcls_bf = (bf16_t*)(ws + (2u << 20) + (128u << 10));    // 160 KB
    bf16_t* h0      = (bf16_t*)(ws + (2u << 20) + (288u << 10));    // 4 MB
    bf16_t* h1      = (bf16_t*)(ws + (6u << 20) + (288u << 10));    // 4 MB
    int*    flags   = (int*)   (ws + (10u << 20) + (288u << 10));   // 64 B

    cvt_whh<<<(HID * HID) / 256, 256, 0, stream>>>(w_hh, whh_bf, HID * HID);
    proj_kernel<<<(VOCAB * HID + 255) / 256, 256, 0, stream>>>(emb, w_ih, proj);
    cvt_wcls<<<(80 * HID) / 256, 256, 0, stream>>>(w_cls, wcls_bf);
    hipMemsetAsync(flags, 0, 16 * sizeof(int), stream);

    const int smem_bytes = 132096 + 16384 + 7424 + 512;   // 156416 B
    hipError_t ce = hipFuncSetAttribute(
        reinterpret_cast<const void*>(rnn_persist),
        hipFuncAttributeMaxDynamicSharedMemorySize, smem_bytes);
    if (ce == hipSuccess) {
        void* args[] = {(void*)&whh_bf, (void*)&proj, (void*)&x,
                        (void*)&h0, (void*)&h1, (void*)&flags};
        ce = hipLaunchCooperativeKernel((void*)rnn_persist, dim3(16, 16),
                                        dim3(256, 1, 1), args, smem_bytes, stream);
    }
    if (ce != hipSuccess) {
        (void)hipGetLastError();   // clear sticky error; proven fallback
        dim3 grid(BATCH / BM, HID / BN);
        bf16_t* bufs[2] = {h0, h1};
        for (int t = 0; t < SEN; t++) {
            bf16_t* hi = bufs[(t + 1) & 1];
            bf16_t* ho = bufs[t & 1];
            rnn_step<<<grid, 256, 0, stream>>>(hi, whh_bf, proj, x, ho, t, t == 0 ? 1 : 0);
        }
    }

    classifier_mfma<<<BATCH / CBM, 256, 0, stream>>>(h1, wcls_bf, b_cls, out);
}